// Round 3
// baseline (431.890 us; speedup 1.0000x reference)
//
#include <hip/hip_runtime.h>
#include <hip/hip_bf16.h>
#include <stdint.h>

// CrossAttention on MI355X (gfx950), bf16 MFMA pipeline.
// R3: flash restructured to key-split waves with ZERO LDS in the main loop.
//   R2 was LDS-throughput-bound: 4 waves re-read identical K/V fragments
//   (80 KB LDS/block-iter, ~50 us/CU of LDS-unit time + 1.27e7 conflict cyc).
//   Now: wave owns 32 keys; Q-frags (loop-invariant) in regs for all 64 q of
//   the block; K/V frags loaded global->reg (L2-hot via XCD swizzle); PV runs
//   at K=32 full rate by concatenating two 16-key S^T C-frags as the A-operand
//   and loading V^T with the agreeing two-b64 split (k-labeling consistency is
//   all MFMA needs). Cross-wave O reduction once per block via LDS tree.

typedef __bf16 bf16_t;
typedef __bf16 bf16x8 __attribute__((ext_vector_type(8)));
typedef __bf16 bf16x4 __attribute__((ext_vector_type(4)));
typedef short  s16x4  __attribute__((ext_vector_type(4)));
typedef float  f32x4  __attribute__((ext_vector_type(4)));

#define BB 4
#define NN 2048
#define KC 2048
#define DD 1024
#define NH 16
#define HD 64
// 0.125 (=HEAD_DIM^-0.5) * log2(e): softmax done in exp2 domain
#define QSCALE 0.18033688011112042f
#define CLIP2  14.426950408889634f

__device__ __forceinline__ f32x4 mfma_16x16x32(bf16x8 a, bf16x8 b, f32x4 c) {
  return __builtin_amdgcn_mfma_f32_16x16x32_bf16(a, b, c, 0, 0, 0);
}

// async global->LDS, 16B per lane; LDS dest is wave-uniform base + lane*16.
__device__ __forceinline__ void gl_lds16(const bf16_t* g, bf16_t* l) {
  __builtin_amdgcn_global_load_lds(
      (const __attribute__((address_space(1))) void*)g,
      (__attribute__((address_space(3))) void*)l, 16, 0, 0);
}

// ---------------- elementwise f32 -> bf16 ----------------
__global__ __launch_bounds__(256) void cvt_f32_bf16(const float* __restrict__ in,
                                                    bf16_t* __restrict__ out, int n4) {
  int i = blockIdx.x * 256 + threadIdx.x;
  if (i >= n4) return;
  float4 v = ((const float4*)in)[i];
  bf16x4 o = {(bf16_t)v.x, (bf16_t)v.y, (bf16_t)v.z, (bf16_t)v.w};
  ((bf16x4*)out)[i] = o;
}

// ---------------- RMSNorm rows of 1024, f32 in -> bf16 out ----------------
__global__ __launch_bounds__(256) void rmsnorm_rows(const float* __restrict__ in,
                                                    bf16_t* __restrict__ out) {
  int row = blockIdx.x, tid = threadIdx.x;
  float4 v = ((const float4*)(in + (size_t)row * DD))[tid];
  float ss = v.x * v.x + v.y * v.y + v.z * v.z + v.w * v.w;
#pragma unroll
  for (int m = 1; m < 64; m <<= 1) ss += __shfl_xor(ss, m);
  __shared__ float wsum[4];
  if ((tid & 63) == 0) wsum[tid >> 6] = ss;
  __syncthreads();
  float total = wsum[0] + wsum[1] + wsum[2] + wsum[3];
  float scale = rsqrtf(total * (1.0f / (float)DD) + 1e-6f);
  bf16x4 o = {(bf16_t)(v.x * scale), (bf16_t)(v.y * scale),
              (bf16_t)(v.z * scale), (bf16_t)(v.w * scale)};
  ((bf16x4*)(out + (size_t)row * DD))[tid] = o;
}

// ---------------- weight transpose: W (R x C) f32 -> WT (C x R) bf16 ----------------
__global__ __launch_bounds__(256) void transpose_w(const float* __restrict__ W,
                                                   bf16_t* __restrict__ WT, int R, int C) {
  __shared__ float tile[32][33];
  int tx = threadIdx.x & 31, ty = threadIdx.x >> 5;
  int r0 = blockIdx.y * 32, c0 = blockIdx.x * 32;
#pragma unroll
  for (int i = 0; i < 4; i++) tile[ty + 8 * i][tx] = W[(size_t)(r0 + ty + 8 * i) * C + c0 + tx];
  __syncthreads();
#pragma unroll
  for (int i = 0; i < 4; i++)
    WT[(size_t)(c0 + ty + 8 * i) * R + r0 + tx] = (bf16_t)tile[tx][ty + 8 * i];
}

// ---------------- GEMM: C(MxN) = (A(MxK) @ Bt(NxK)^T + bias) * alpha ----------------
template <int OUT_F32>
__global__ __launch_bounds__(256, 2) void gemm_bt(const bf16_t* __restrict__ A,
                                                  const bf16_t* __restrict__ Bt,
                                                  const float* __restrict__ bias,
                                                  void* __restrict__ Cout, int M, int N,
                                                  int Kd, float alpha) {
  __shared__ bf16_t As[128 * 32];
  __shared__ bf16_t Bs[128 * 32];
  int tid = threadIdx.x;
  int w = tid >> 6, lane = tid & 63;
  int quad = lane >> 4, l16 = lane & 15;
  int row0 = blockIdx.y * 128, col0 = blockIdx.x * 128;
  int wm = (w >> 1) * 64, wn = (w & 1) * 64;

  f32x4 acc[4][4];
#pragma unroll
  for (int i = 0; i < 4; i++)
#pragma unroll
    for (int j = 0; j < 4; j++) acc[i][j] = (f32x4){0.f, 0.f, 0.f, 0.f};

  for (int kk = 0; kk < Kd; kk += 32) {
#pragma unroll
    for (int call = 0; call < 2; call++) {
      int c = w * 128 + call * 64 + lane;
      gl_lds16(&A[(size_t)(row0 + (c >> 2)) * Kd + kk + (c & 3) * 8],
               &As[(w * 128 + call * 64) * 8]);
      gl_lds16(&Bt[(size_t)(col0 + (c >> 2)) * Kd + kk + (c & 3) * 8],
               &Bs[(w * 128 + call * 64) * 8]);
    }
    __syncthreads();
    bf16x8 af[4], bfr[4];
#pragma unroll
    for (int mi = 0; mi < 4; mi++)
      af[mi] = *(const bf16x8*)&As[(wm + mi * 16 + l16) * 32 + quad * 8];
#pragma unroll
    for (int ni = 0; ni < 4; ni++)
      bfr[ni] = *(const bf16x8*)&Bs[(wn + ni * 16 + l16) * 32 + quad * 8];
#pragma unroll
    for (int mi = 0; mi < 4; mi++)
#pragma unroll
      for (int ni = 0; ni < 4; ni++) acc[mi][ni] = mfma_16x16x32(af[mi], bfr[ni], acc[mi][ni]);
    __syncthreads();
  }

#pragma unroll
  for (int ni = 0; ni < 4; ni++) {
    int col = col0 + wn + ni * 16 + l16;
    float bv = bias[col];
#pragma unroll
    for (int mi = 0; mi < 4; mi++) {
#pragma unroll
      for (int r = 0; r < 4; r++) {
        int row = row0 + wm + mi * 16 + quad * 4 + r;
        float v = (acc[mi][ni][r] + bv) * alpha;
        if (OUT_F32)
          ((float*)Cout)[(size_t)row * N + col] = v;
        else
          ((bf16_t*)Cout)[(size_t)row * N + col] = (bf16_t)v;
      }
    }
  }
}

// ---------------- V repack: kvbuf[b][kc][1024+h*64+hd] -> vT[(b,h)][hd][kc] ----------------
__global__ __launch_bounds__(256) void transpose_v(const bf16_t* __restrict__ kvbuf,
                                                   bf16_t* __restrict__ vT) {
  __shared__ bf16_t tile[64][72];
  int bh = blockIdx.y;
  int b = bh >> 4, h = bh & 15;
  int kc0 = blockIdx.x * 64;
  int tid = threadIdx.x;
#pragma unroll
  for (int i = 0; i < 2; i++) {
    int ch = tid + i * 256;
    int key = ch >> 3, cc = ch & 7;
    *(bf16x8*)&tile[key][cc * 8] =
        *(const bf16x8*)&kvbuf[((size_t)b * KC + kc0 + key) * (2 * DD) + DD + h * HD + cc * 8];
  }
  __syncthreads();
#pragma unroll
  for (int i = 0; i < 2; i++) {
    int ch = tid + i * 256;
    int hd = ch >> 3, cc = ch & 7;
    bf16x8 v;
#pragma unroll
    for (int e = 0; e < 8; e++) v[e] = tile[cc * 8 + e][hd];
    *(bf16x8*)&vT[((size_t)bh * HD + hd) * KC + kc0 + cc * 8] = v;
  }
}

// ---------------- flash attention, key-split waves, no LDS in main loop ----------------
// Block: 64 q-rows, 4 waves; wave w owns keys [kc0+w*32, +32) each iter (kc0 += 128).
// Q-frags (loop-invariant) + K/V frags all in registers; K/V read straight from
// global (L2-hot, XCD swizzle). S^T = K*Q^T per 16-key group; two groups' C-frags
// concatenate into the K=32 PV A-operand (k-labeling: slot(quad,j) = grp(j>=4),
// key quad*4+(j&3)); V^T B-frag loaded with the same split -> full-rate PV.
// Cross-wave O reduction (different key sets) via LDS tree at the end.
__global__ __launch_bounds__(256, 3) void flash_attn(const bf16_t* __restrict__ qbuf,
                                                     const bf16_t* __restrict__ kvbuf,
                                                     const bf16_t* __restrict__ vT,
                                                     bf16_t* __restrict__ attn_out) {
  __shared__ float Obuf[2][64][68];  // [buf][hd][q], pitch 68
  __shared__ float rsh[4][64];
  __shared__ float rsinv[64];
  __shared__ bf16_t outS[64][72];    // [q][hd] staging for coalesced store

  int tid = threadIdx.x, w = tid >> 6, lane = tid & 63;
  int quad = lane >> 4, l16 = lane & 15;
  // XCD swizzle: 2048 blocks; xcd = bid&7 gets 8 whole (b,h) -> K/V L2-local.
  int bid = blockIdx.x;
  int xcd = bid & 7, slot = bid >> 3;
  int bh = xcd * 8 + (slot >> 5);
  int qt = slot & 31;
  int b = bh >> 4, h = bh & 15;
  int n0 = qt * 64;

  const size_t kvbase = (size_t)b * KC * (2 * DD) + (size_t)h * HD;
  const size_t vtbase = (size_t)bh * HD * KC;

  // Q-frags: B-operand of S^T. B[k=d=quad*8+j][n=query=qi*16+l16].
  bf16x8 qf[4][2];
#pragma unroll
  for (int qi = 0; qi < 4; qi++)
#pragma unroll
    for (int dc = 0; dc < 2; dc++)
      qf[qi][dc] = *(const bf16x8*)&qbuf[((size_t)b * NN + n0 + qi * 16 + l16) * DD + h * HD +
                                         dc * 32 + quad * 8];

  f32x4 o[4][4];  // [qi][hb], C: row=quad*4+r = q-within-16, col=l16 = hd-within-16
#pragma unroll
  for (int qi = 0; qi < 4; qi++)
#pragma unroll
    for (int hb = 0; hb < 4; hb++) o[qi][hb] = (f32x4){0.f, 0.f, 0.f, 0.f};
  float rs[4] = {0.f, 0.f, 0.f, 0.f};

  for (int kc0 = 0; kc0 < KC; kc0 += 128) {
    int wk = kc0 + w * 32;  // this wave's 32 keys
    // K frags: A[m=key=l16][k=d=quad*8+j], per 16-key group, per d-half.
    bf16x8 kf[2][2];
#pragma unroll
    for (int g = 0; g < 2; g++)
#pragma unroll
      for (int dc = 0; dc < 2; dc++)
        kf[g][dc] = *(const bf16x8*)&kvbuf[kvbase + (size_t)(wk + g * 16 + l16) * (2 * DD) +
                                           dc * 32 + quad * 8];
    // V frags: B[k-slot(quad,j)][n=hd=hb*16+l16], slot j<4 -> grp0 key quad*4+j,
    // j>=4 -> grp1 key 16+quad*4+(j-4): two b64s, same labeling as P concat.
    union {
      bf16x8 v8;
      s16x4 h[2];
    } vB[4];
#pragma unroll
    for (int hb = 0; hb < 4; hb++) {
      const bf16_t* vrow = &vT[vtbase + (size_t)(hb * 16 + l16) * KC + wk + quad * 4];
      vB[hb].h[0] = *(const s16x4*)(vrow);
      vB[hb].h[1] = *(const s16x4*)(vrow + 16);
    }

#pragma unroll
    for (int qi = 0; qi < 4; qi++) {
      union {
        bf16x8 v8;
        bf16x4 h[2];
      } pf;
#pragma unroll
      for (int g = 0; g < 2; g++) {
        f32x4 s = (f32x4){0.f, 0.f, 0.f, 0.f};
        s = mfma_16x16x32(kf[g][0], qf[qi][0], s);
        s = mfma_16x16x32(kf[g][1], qf[qi][1], s);
        bf16x4 pb;
#pragma unroll
        for (int r = 0; r < 4; r++) {
          float p = __builtin_amdgcn_exp2f(__builtin_amdgcn_fmed3f(s[r], -CLIP2, CLIP2));
          rs[qi] += p;
          pb[r] = (bf16_t)p;
        }
        pf.h[g] = pb;
      }
#pragma unroll
      for (int hb = 0; hb < 4; hb++) o[qi][hb] = mfma_16x16x32(pf.v8, vB[hb].v8, o[qi][hb]);
    }
  }

  // ---- cross-wave reduction (each wave covered a different key subset) ----
  // rs: sum over quads -> per-wave row-sum for query qi*16+l16.
#pragma unroll
  for (int qi = 0; qi < 4; qi++) {
    float v = rs[qi];
    v += __shfl_xor(v, 16);
    v += __shfl_xor(v, 32);
    if (quad == 0) rsh[w][qi * 16 + l16] = v;
  }
  if (w >= 2) {  // waves 2,3 publish O partials
#pragma unroll
    for (int qi = 0; qi < 4; qi++)
#pragma unroll
      for (int hb = 0; hb < 4; hb++)
        *(f32x4*)&Obuf[w - 2][hb * 16 + l16][qi * 16 + quad * 4] = o[qi][hb];
  }
  __syncthreads();
  if (w < 2) {  // waves 0,1 absorb
#pragma unroll
    for (int qi = 0; qi < 4; qi++)
#pragma unroll
      for (int hb = 0; hb < 4; hb++)
        o[qi][hb] += *(const f32x4*)&Obuf[w][hb * 16 + l16][qi * 16 + quad * 4];
  }
  if (w == 2) rsinv[lane] = 1.0f / (rsh[0][lane] + rsh[1][lane] + rsh[2][lane] + rsh[3][lane]);
  __syncthreads();
  if (w == 1) {
#pragma unroll
    for (int qi = 0; qi < 4; qi++)
#pragma unroll
      for (int hb = 0; hb < 4; hb++)
        *(f32x4*)&Obuf[0][hb * 16 + l16][qi * 16 + quad * 4] = o[qi][hb];
  }
  __syncthreads();
  if (w == 0) {
#pragma unroll
    for (int qi = 0; qi < 4; qi++) {
      f32x4 ri = *(const f32x4*)&rsinv[qi * 16 + quad * 4];
#pragma unroll
      for (int hb = 0; hb < 4; hb++) {
        f32x4 ov = o[qi][hb] + *(const f32x4*)&Obuf[0][hb * 16 + l16][qi * 16 + quad * 4];
#pragma unroll
        for (int r = 0; r < 4; r++)
          outS[qi * 16 + quad * 4 + r][hb * 16 + l16] = (bf16_t)(ov[r] * ri[r]);
      }
    }
  }
  __syncthreads();
#pragma unroll
  for (int i = 0; i < 2; i++) {
    int idx = tid + i * 256;
    int row = idx >> 3, c = idx & 7;
    *(bf16x8*)&attn_out[((size_t)b * NN + n0 + row) * DD + h * HD + c * 8] =
        *(const bf16x8*)&outS[row][c * 8];
  }
}

__global__ void write_mean(float* out) { out[0] = 1.0f / 2048.0f; }

// ---------------- launch ----------------
extern "C" void kernel_launch(void* const* d_in, const int* in_sizes, int n_in, void* d_out,
                              int out_size, void* d_ws, size_t ws_size, hipStream_t stream) {
  const float* x      = (const float*)d_in[0];
  const float* ctx    = (const float*)d_in[1];
  const float* q_w    = (const float*)d_in[2];
  const float* q_b    = (const float*)d_in[3];
  const float* kv_w   = (const float*)d_in[4];
  const float* kv_b   = (const float*)d_in[5];
  const float* proj_w = (const float*)d_in[6];
  const float* proj_b = (const float*)d_in[7];
  float* out = (float*)d_out;
  char* ws = (char*)d_ws;

  bf16_t* xb    = (bf16_t*)(ws + 0);          // 16 MB, dead after q GEMM
  bf16_t* ctxn  = (bf16_t*)(ws + 16777216);   // 16 MB, dead after kv GEMM
  bf16_t* qwT   = (bf16_t*)(ws + 33554432);   // 2 MB
  bf16_t* kvwT  = (bf16_t*)(ws + 35651584);   // 4 MB
  bf16_t* pwT   = (bf16_t*)(ws + 39845888);   // 2 MB
  bf16_t* qbuf  = (bf16_t*)(ws + 41943040);   // 16 MB
  bf16_t* kvbuf = (bf16_t*)(ws + 58720256);   // 32 MB
  bf16_t* vT       = ctxn;                    // alias: written after ctxn consumed
  bf16_t* attn_out = xb;                      // alias: written after xb consumed

  cvt_f32_bf16<<<8192, 256, 0, stream>>>(x, xb, (BB * NN * DD) / 4);
  rmsnorm_rows<<<BB * KC, 256, 0, stream>>>(ctx, ctxn);
  transpose_w<<<dim3(32, 32), 256, 0, stream>>>(q_w, qwT, DD, DD);
  transpose_w<<<dim3(64, 32), 256, 0, stream>>>(kv_w, kvwT, DD, 2 * DD);
  transpose_w<<<dim3(32, 32), 256, 0, stream>>>(proj_w, pwT, DD, DD);
  // q = (x @ q_w + q_b) * (SCALE*log2e)  -> softmax uses exp2
  gemm_bt<0><<<dim3(8, 64), 256, 0, stream>>>(xb, qwT, q_b, qbuf, BB * NN, DD, DD, QSCALE);
  gemm_bt<0><<<dim3(16, 64), 256, 0, stream>>>(ctxn, kvwT, kv_b, kvbuf, BB * KC, 2 * DD, DD, 1.0f);
  transpose_v<<<dim3(KC / 64, BB * NH), 256, 0, stream>>>(kvbuf, vT);
  flash_attn<<<2048, 256, 0, stream>>>(qbuf, kvbuf, vT, attn_out);
  gemm_bt<1><<<dim3(8, 64), 256, 0, stream>>>(attn_out, pwT, proj_b, out, BB * NN, DD, DD, 1.0f);
  write_mean<<<1, 1, 0, stream>>>(out + (size_t)out_size - 1);
}